// Round 3
// baseline (290.495 us; speedup 1.0000x reference)
//
#include <hip/hip_runtime.h>

#define B_DIM 512
#define T_DIM 4096
#define NSLOT 256
#define BLOCKS 4096
#define THREADS 256
#define ITER 8   // (512*4096*4 quarter-rows) / (4096*256 threads)

__device__ __forceinline__ float hsum4(float4 v) { return (v.x + v.y) + (v.z + v.w); }

__device__ __forceinline__ float mdot(float4 x, float4 m) {
    return (x.x * m.x + x.y * m.y) + (x.z * m.z + x.w * m.w);
}

__device__ __forceinline__ float mdot2(float4 x, float4 m) {
    return (x.x * x.x * m.x + x.y * x.y * m.y) + (x.z * x.z * m.z + x.w * x.w * m.w);
}

// Sum across an aligned 4-lane quad via DPP quad_perm (pure VALU, no LDS pipe).
__device__ __forceinline__ float qsum(float v) {
    int t = __builtin_amdgcn_update_dpp(0, __float_as_int(v), 0xB1, 0xF, 0xF, true); // [1,0,3,2] xor1
    v += __int_as_float(t);
    t = __builtin_amdgcn_update_dpp(0, __float_as_int(v), 0x4E, 0xF, 0xF, true);     // [2,3,0,1] xor2
    v += __int_as_float(t);
    return v;
}

// 4 lanes per (b,t) row, one float4 each -> fully coalesced. All loads up front.
__global__ __launch_bounds__(THREADS) void rcl_main(
    const float4* __restrict__ pred4, const float4* __restrict__ targ4,
    const float4* __restrict__ mask4, double* __restrict__ slots)
{
    const int tid0 = blockIdx.x * THREADS + threadIdx.x;

    float4 mv[ITER], pv[ITER], qv[ITER];
#pragma unroll
    for (int i = 0; i < ITER; i++) {
        const int g = tid0 + i * (BLOCKS * THREADS);
        pv[i] = pred4[g];
        qv[i] = targ4[g];
        mv[i] = mask4[((g >> 14) << 2) + (g & 3)];  // b = g >> 14 (row>>12, row=g>>2)
    }

    float csum = 0.0f;
#pragma unroll
    for (int i = 0; i < ITER; i++) {
        const float4 m = mv[i], p = pv[i], q = qv[i];
        float n   = qsum(hsum4(m));
        float sp  = qsum(mdot(p, m));
        float sp2 = qsum(mdot2(p, m));
        float sq  = qsum(mdot(q, m));
        float sq2 = qsum(mdot2(q, m));

        float nsafe = fmaxf(n, 2.0f);
        float inv = 1.0f / (nsafe * (nsafe - 1.0f));
        // unbiased var = (n*s2 - s*s) / (n*(n-1)); n_safe == n for valid rows
        float d = ((nsafe * sp2 - sp * sp) - (nsafe * sq2 - sq * sq)) * inv;
        csum += (n > 1.0f) ? d * d * 0.25f : 0.0f;  // each of 4 lanes holds dd -> 0.25
    }

    for (int off = 32; off > 0; off >>= 1)
        csum += __shfl_down(csum, off, 64);

    __shared__ float partial[THREADS / 64];
    const int lane = threadIdx.x & 63;
    const int w = threadIdx.x >> 6;
    if (lane == 0) partial[w] = csum;
    __syncthreads();
    if (threadIdx.x == 0) {
        float s = (partial[0] + partial[1]) + (partial[2] + partial[3]);
        atomicAdd(&slots[blockIdx.x & (NSLOT - 1)], (double)s);
    }
}

__global__ __launch_bounds__(256) void rcl_final(
    const double* __restrict__ slots, const float4* __restrict__ mask4,
    float* __restrict__ out)
{
    __shared__ double dred[256];
    __shared__ float fred[256];
    const int t = threadIdx.x;

    double tot = slots[t];

    float cnt = 0.0f;
    for (int bb = t; bb < B_DIM; bb += 256) {
        const float4* mp = mask4 + (bb << 2);
        float nn = (hsum4(mp[0]) + hsum4(mp[1])) + (hsum4(mp[2]) + hsum4(mp[3]));
        cnt += (nn > 1.0f) ? 1.0f : 0.0f;
    }

    dred[t] = tot;
    fred[t] = cnt;
    __syncthreads();
    for (int s = 128; s > 0; s >>= 1) {
        if (t < s) { dred[t] += dred[t + s]; fred[t] += fred[t + s]; }
        __syncthreads();
    }
    if (t == 0) {
        double nm = (double)fred[0];
        out[0] = (nm > 0.0) ? (float)(0.1 * (dred[0] / ((double)T_DIM * nm))) : 0.0f;
    }
}

extern "C" void kernel_launch(void* const* d_in, const int* in_sizes, int n_in,
                              void* d_out, int out_size, void* d_ws, size_t ws_size,
                              hipStream_t stream) {
    const float4* pred4 = (const float4*)d_in[0];
    const float4* targ4 = (const float4*)d_in[1];
    const float4* mask4 = (const float4*)d_in[2];
    float* out = (float*)d_out;

    double* slots = (double*)d_ws;  // NSLOT doubles

    hipMemsetAsync(d_ws, 0, NSLOT * sizeof(double), stream);
    rcl_main<<<BLOCKS, THREADS, 0, stream>>>(pred4, targ4, mask4, slots);
    rcl_final<<<1, 256, 0, stream>>>(slots, mask4, out);
}

// Round 4
// 290.394 us; speedup vs baseline: 1.0003x; 1.0003x over previous
//
#include <hip/hip_runtime.h>

#define B_DIM 512
#define T_DIM 4096
#define BLOCKS 8192
#define THREADS 256
#define ITER 4   // (512*4096*4 quarter-rows) / (8192*256 threads)

__device__ __forceinline__ float hsum4(float4 v) { return (v.x + v.y) + (v.z + v.w); }

__device__ __forceinline__ float mdot(float4 x, float4 m) {
    return (x.x * m.x + x.y * m.y) + (x.z * m.z + x.w * m.w);
}

__device__ __forceinline__ float mdot2(float4 x, float4 m) {
    return (x.x * x.x * m.x + x.y * x.y * m.y) + (x.z * x.z * m.z + x.w * x.w * m.w);
}

// Sum across an aligned 4-lane quad via DPP quad_perm (pure VALU, no LDS pipe).
__device__ __forceinline__ float qsum(float v) {
    int t = __builtin_amdgcn_update_dpp(0, __float_as_int(v), 0xB1, 0xF, 0xF, true); // xor1
    v += __int_as_float(t);
    t = __builtin_amdgcn_update_dpp(0, __float_as_int(v), 0x4E, 0xF, 0xF, true);     // xor2
    v += __int_as_float(t);
    return v;
}

// 4 lanes per (b,t) row, one float4 each -> fully coalesced.
// sched_barrier(0) pins ALL loads before ANY compute -> ~12 KB in flight/wave.
__global__ __launch_bounds__(THREADS) void rcl_main(
    const float4* __restrict__ pred4, const float4* __restrict__ targ4,
    const float4* __restrict__ mask4, double* __restrict__ slots)
{
    const int tid0 = blockIdx.x * THREADS + threadIdx.x;

    float4 mv[ITER], pv[ITER], qv[ITER];
#pragma unroll
    for (int i = 0; i < ITER; i++) {
        const int g = tid0 + i * (BLOCKS * THREADS);
        pv[i] = pred4[g];
        qv[i] = targ4[g];
        mv[i] = mask4[((g >> 14) << 2) + (g & 3)];  // b = g >> 14
    }

    __builtin_amdgcn_sched_barrier(0);  // keep every load issued before compute

    float csum = 0.0f;
#pragma unroll
    for (int i = 0; i < ITER; i++) {
        const float4 m = mv[i], p = pv[i], q = qv[i];
        float n   = qsum(hsum4(m));
        float sp  = qsum(mdot(p, m));
        float sp2 = qsum(mdot2(p, m));
        float sq  = qsum(mdot(q, m));
        float sq2 = qsum(mdot2(q, m));

        float nsafe = fmaxf(n, 2.0f);
        float inv = 1.0f / (nsafe * (nsafe - 1.0f));
        float d = ((nsafe * sp2 - sp * sp) - (nsafe * sq2 - sq * sq)) * inv;
        csum += (n > 1.0f) ? d * d * 0.25f : 0.0f;
    }

    for (int off = 32; off > 0; off >>= 1)
        csum += __shfl_down(csum, off, 64);

    __shared__ float partial[THREADS / 64];
    const int lane = threadIdx.x & 63;
    const int w = threadIdx.x >> 6;
    if (lane == 0) partial[w] = csum;
    __syncthreads();
    if (threadIdx.x == 0) {
        float s = (partial[0] + partial[1]) + (partial[2] + partial[3]);
        slots[blockIdx.x] = (double)s;   // plain store, no init needed
    }
}

// Reduce 8192 per-block slots + recompute n_multi from the (cached) mask.
__global__ __launch_bounds__(256) void rcl_final(
    const double* __restrict__ slots, const float4* __restrict__ mask4,
    float* __restrict__ out)
{
    __shared__ double dred[256];
    __shared__ float fred[256];
    const int t = threadIdx.x;

    double tot = 0.0;
    for (int i = t; i < BLOCKS; i += 256) tot += slots[i];

    float cnt = 0.0f;
    for (int bb = t; bb < B_DIM; bb += 256) {
        const float4* mp = mask4 + (bb << 2);
        float nn = (hsum4(mp[0]) + hsum4(mp[1])) + (hsum4(mp[2]) + hsum4(mp[3]));
        cnt += (nn > 1.0f) ? 1.0f : 0.0f;
    }

    dred[t] = tot;
    fred[t] = cnt;
    __syncthreads();
    for (int s = 128; s > 0; s >>= 1) {
        if (t < s) { dred[t] += dred[t + s]; fred[t] += fred[t + s]; }
        __syncthreads();
    }
    if (t == 0) {
        double nm = (double)fred[0];
        out[0] = (nm > 0.0) ? (float)(0.1 * (dred[0] / ((double)T_DIM * nm))) : 0.0f;
    }
}

extern "C" void kernel_launch(void* const* d_in, const int* in_sizes, int n_in,
                              void* d_out, int out_size, void* d_ws, size_t ws_size,
                              hipStream_t stream) {
    const float4* pred4 = (const float4*)d_in[0];
    const float4* targ4 = (const float4*)d_in[1];
    const float4* mask4 = (const float4*)d_in[2];
    float* out = (float*)d_out;

    double* slots = (double*)d_ws;  // BLOCKS doubles = 64 KB

    rcl_main<<<BLOCKS, THREADS, 0, stream>>>(pred4, targ4, mask4, slots);
    rcl_final<<<1, 256, 0, stream>>>(slots, mask4, out);
}

// Round 5
// 267.945 us; speedup vs baseline: 1.0842x; 1.0838x over previous
//
#include <hip/hip_runtime.h>

#define B_DIM 512
#define T_DIM 4096
#define NSLOT 256
#define BLOCKS 16384
#define THREADS 256
#define NWAVE (THREADS / 64)
#define ITER 2   // (512*4096*4 quarter-rows) / (16384*256 threads)

__device__ __forceinline__ float hsum4(float4 v) { return (v.x + v.y) + (v.z + v.w); }

__device__ __forceinline__ float mdot(float4 x, float4 m) {
    return (x.x * m.x + x.y * m.y) + (x.z * m.z + x.w * m.w);
}

__device__ __forceinline__ float mdot2(float4 x, float4 m) {
    return (x.x * x.x * m.x + x.y * x.y * m.y) + (x.z * x.z * m.z + x.w * x.w * m.w);
}

// Sum across an aligned 4-lane quad via DPP quad_perm (pure VALU).
__device__ __forceinline__ float qsum(float v) {
    int t = __builtin_amdgcn_update_dpp(0, __float_as_int(v), 0xB1, 0xF, 0xF, true); // xor1
    v += __int_as_float(t);
    t = __builtin_amdgcn_update_dpp(0, __float_as_int(v), 0x4E, 0xF, 0xF, true);     // xor2
    v += __int_as_float(t);
    return v;
}

// Async global->LDS, 16 B/lane, no VGPR result => compiler can't serialize MLP.
__device__ __forceinline__ void stage16(const float4* g, float4* l) {
    __builtin_amdgcn_global_load_lds((const __attribute__((address_space(1))) void*)g,
                                     (__attribute__((address_space(3))) void*)l, 16, 0, 0);
}

// 4 lanes per (b,t) row. Stage pred/targ via global_load_lds into per-wave LDS,
// one vmcnt drain, compute from LDS. Invalid batches (n<=1, block-uniform per
// iter) skip staging entirely.
__global__ __launch_bounds__(THREADS) void rcl_main(
    const float4* __restrict__ pred4, const float4* __restrict__ targ4,
    const float4* __restrict__ mask4, double* __restrict__ slots)
{
    // [array][wave][iter][lane] : 2*4*2*64*16 B = 16 KB
    __shared__ float4 buf[2][NWAVE][ITER][64];

    const int tid = threadIdx.x;
    const int w = tid >> 6;
    const int lane = tid & 63;
    const int tid0 = blockIdx.x * THREADS + tid;

    // mask parts first (32 KB array, L1/L2-hot)
    float4 mv[ITER];
#pragma unroll
    for (int i = 0; i < ITER; i++) {
        const int g = tid0 + i * (BLOCKS * THREADS);
        mv[i] = mask4[((g >> 14) << 2) + (g & 3)];  // b = g >> 14, wave-uniform
    }

    float nval[ITER];
#pragma unroll
    for (int i = 0; i < ITER; i++) {
        const int g = tid0 + i * (BLOCKS * THREADS);
        nval[i] = qsum(hsum4(mv[i]));               // n, block-uniform per iter
        if (nval[i] > 1.0f) {
            stage16(&pred4[g], &buf[0][w][i][0]);
            stage16(&targ4[g], &buf[1][w][i][0]);
        }
    }

    __syncthreads();  // drains vmcnt; per-wave regions only, barrier cost minor

    float csum = 0.0f;
#pragma unroll
    for (int i = 0; i < ITER; i++) {
        if (nval[i] > 1.0f) {
            const float4 m = mv[i];
            const float4 p = buf[0][w][i][lane];
            const float4 q = buf[1][w][i][lane];
            float sp  = qsum(mdot(p, m));
            float sp2 = qsum(mdot2(p, m));
            float sq  = qsum(mdot(q, m));
            float sq2 = qsum(mdot2(q, m));

            const float n = nval[i];
            float inv = 1.0f / (n * (n - 1.0f));
            // unbiased var = (n*s2 - s*s) / (n*(n-1))
            float d = ((n * sp2 - sp * sp) - (n * sq2 - sq * sq)) * inv;
            csum += d * d * 0.25f;  // 4 lanes hold identical d^2
        }
    }

    for (int off = 32; off > 0; off >>= 1)
        csum += __shfl_down(csum, off, 64);

    __shared__ float partial[NWAVE];
    if (lane == 0) partial[w] = csum;
    __syncthreads();
    if (tid == 0) {
        float s = (partial[0] + partial[1]) + (partial[2] + partial[3]);
        atomicAdd(&slots[blockIdx.x & (NSLOT - 1)], (double)s);
    }
}

// Reduce 256 slots + recompute n_multi from the (cached) mask.
__global__ __launch_bounds__(256) void rcl_final(
    const double* __restrict__ slots, const float4* __restrict__ mask4,
    float* __restrict__ out)
{
    __shared__ double dred[256];
    __shared__ float fred[256];
    const int t = threadIdx.x;

    double tot = slots[t];

    float cnt = 0.0f;
    for (int bb = t; bb < B_DIM; bb += 256) {
        const float4* mp = mask4 + (bb << 2);
        float nn = (hsum4(mp[0]) + hsum4(mp[1])) + (hsum4(mp[2]) + hsum4(mp[3]));
        cnt += (nn > 1.0f) ? 1.0f : 0.0f;
    }

    dred[t] = tot;
    fred[t] = cnt;
    __syncthreads();
    for (int s = 128; s > 0; s >>= 1) {
        if (t < s) { dred[t] += dred[t + s]; fred[t] += fred[t + s]; }
        __syncthreads();
    }
    if (t == 0) {
        double nm = (double)fred[0];
        out[0] = (nm > 0.0) ? (float)(0.1 * (dred[0] / ((double)T_DIM * nm))) : 0.0f;
    }
}

extern "C" void kernel_launch(void* const* d_in, const int* in_sizes, int n_in,
                              void* d_out, int out_size, void* d_ws, size_t ws_size,
                              hipStream_t stream) {
    const float4* pred4 = (const float4*)d_in[0];
    const float4* targ4 = (const float4*)d_in[1];
    const float4* mask4 = (const float4*)d_in[2];
    float* out = (float*)d_out;

    double* slots = (double*)d_ws;  // NSLOT doubles

    hipMemsetAsync(d_ws, 0, NSLOT * sizeof(double), stream);
    rcl_main<<<BLOCKS, THREADS, 0, stream>>>(pred4, targ4, mask4, slots);
    rcl_final<<<1, 256, 0, stream>>>(slots, mask4, out);
}